// Round 12
// baseline (676.035 us; speedup 1.0000x reference)
//
#include <hip/hip_runtime.h>
#include <math.h>

#define BB 32
#define LL 128
#define DM 64
#define DI 128
#define NV 50001
#define BL (BB*LL)       // 4096
#define TM 32
#define TN 256
#define NT3 196          // ceil(50001/256)
#define NPAD3 (NT3*TN)   // 50176
#define CPX 261          // C tile pitch: >= 259 (shift+255+3 reads), %4==1 (alignment trick)

typedef float f32x4 __attribute__((ext_vector_type(4)));
typedef _Float16 h16x8 __attribute__((ext_vector_type(8)));

__device__ __forceinline__ float silu_f(float x) { return x / (1.0f + expf(-x)); }

// ================= fused pre-chain: embed + in_proj + conv + silu + x_proj + delta ==========
__global__ __launch_bounds__(512, 1) void k_pre(
    const int* __restrict__ ids, const float* __restrict__ item_emb,
    const float* __restrict__ pos_emb, const float* __restrict__ in_proj_w,
    const float* __restrict__ conv_w, const float* __restrict__ conv_b,
    const float* __restrict__ x_proj_w, const float* __restrict__ dt_proj_w,
    const float* __restrict__ dt_proj_b,
    float* __restrict__ zs_g, float* __restrict__ xcs_g,
    float* __restrict__ dbl_g, float* __restrict__ delta_g) {
    __shared__ float sq[67 * 68];
    __shared__ float px[67 * 132];
    __shared__ float cvS[64 * 132];
    __shared__ float dblS[64 * 68];
    const int t = threadIdx.x;
    const int bb = blockIdx.x >> 1, half = blockIdx.x & 1;
    const int l0 = half * 64;

    {
        int d = t & 63;
        for (int i = t >> 6; i < 67; i += 8) {
            int tl = l0 - 3 + i;
            float v = 0.f;
            if (tl >= 0) {
                int id = ids[bb * LL + tl];
                if (id != 0) v = item_emb[id * DM + d] * 8.0f + pos_emb[tl * DM + d];
            }
            sq[i * 68 + d] = v;
        }
    }
    __syncthreads();
    {
        int r = t & 63;
        int q = __builtin_amdgcn_readfirstlane(t >> 6);
        f32x4 s4[16];
        #pragma unroll
        for (int k = 0; k < 16; k++) s4[k] = *(const f32x4*)&sq[r * 68 + 4 * k];
        float acc[32];
        #pragma unroll
        for (int j = 0; j < 32; j++) acc[j] = 0.f;
        const float* wq = in_proj_w + (q * 32) * DM;
        #pragma unroll 4
        for (int j = 0; j < 32; j++) {
            float a = 0.f;
            #pragma unroll
            for (int k = 0; k < 16; k++) {
                f32x4 w4 = *(const f32x4*)&wq[j * DM + 4 * k];
                a += s4[k].x * w4.x + s4[k].y * w4.y + s4[k].z * w4.z + s4[k].w * w4.w;
            }
            acc[j] = a;
        }
        int tok = l0 - 3 + r;
        if (q < 4) {
            #pragma unroll
            for (int j4 = 0; j4 < 8; j4++) {
                f32x4 v = {acc[4 * j4], acc[4 * j4 + 1], acc[4 * j4 + 2], acc[4 * j4 + 3]};
                *(f32x4*)&px[r * 132 + q * 32 + 4 * j4] = v;
            }
        } else if (tok >= 0) {
            float* dst = zs_g + (size_t)(bb * LL + tok) * DI + (q - 4) * 32;
            #pragma unroll
            for (int j = 0; j < 32; j++) dst[j] = silu_f(acc[j]);
        }
    }
    __syncthreads();
    {
        int e = t & 255;
        for (int hr = 64 + (t >> 8); hr < 67; hr += 2) {
            float a = 0.f;
            const float* w = in_proj_w + e * DM;
            #pragma unroll
            for (int k = 0; k < 16; k++) {
                f32x4 sv = *(const f32x4*)&sq[hr * 68 + 4 * k];
                f32x4 wv = *(const f32x4*)&w[4 * k];
                a += sv.x * wv.x + sv.y * wv.y + sv.z * wv.z + sv.w * wv.w;
            }
            int tok = l0 - 3 + hr;
            if (e < 128) px[hr * 132 + e] = a;
            else zs_g[(size_t)(bb * LL + tok) * DI + (e - 128)] = silu_f(a);
        }
    }
    __syncthreads();
    {
        int c = t & 127, r4 = t >> 7;
        float cw0 = conv_w[c * 4], cw1 = conv_w[c * 4 + 1];
        float cw2 = conv_w[c * 4 + 2], cw3 = conv_w[c * 4 + 3];
        float cb = conv_b[c];
        for (int g = 0; g < 16; g++) {
            int j = 4 * g + r4;
            float x0 = px[j * 132 + c], x1 = px[(j + 1) * 132 + c];
            float x2 = px[(j + 2) * 132 + c], x3 = px[(j + 3) * 132 + c];
            float v = silu_f(cb + x0 * cw0 + x1 * cw1 + x2 * cw2 + x3 * cw3);
            cvS[j * 132 + c] = v;
            xcs_g[(size_t)(bb * LL + l0 + j) * DI + c] = v;
        }
    }
    __syncthreads();
    {
        int r = t & 63;
        int q = __builtin_amdgcn_readfirstlane(t >> 6);
        int e0 = q * 9;
        float acc[9];
        #pragma unroll
        for (int j = 0; j < 9; j++) acc[j] = 0.f;
        #pragma unroll
        for (int kc = 0; kc < 4; kc++) {
            f32x4 xr[8];
            #pragma unroll
            for (int k4 = 0; k4 < 8; k4++)
                xr[k4] = *(const f32x4*)&cvS[r * 132 + kc * 32 + 4 * k4];
            #pragma unroll
            for (int j = 0; j < 9; j++) {
                int e = e0 + j;
                if (e < 68) {
                    const float* w = x_proj_w + (size_t)e * DI + kc * 32;
                    float a = acc[j];
                    #pragma unroll
                    for (int k4 = 0; k4 < 8; k4++) {
                        f32x4 wv = *(const f32x4*)&w[4 * k4];
                        a += xr[k4].x * wv.x + xr[k4].y * wv.y + xr[k4].z * wv.z + xr[k4].w * wv.w;
                    }
                    acc[j] = a;
                }
            }
        }
        int row = bb * LL + l0 + r;
        #pragma unroll
        for (int j = 0; j < 9; j++) {
            int e = e0 + j;
            if (e < 68) {
                dblS[r * 68 + e] = acc[j];
                if (e >= 4) dbl_g[(size_t)row * 64 + (e - 4)] = acc[j];
            }
        }
    }
    __syncthreads();
    {
        int r = t & 63;
        int q = __builtin_amdgcn_readfirstlane(t >> 6);
        f32x4 dt = *(const f32x4*)&dblS[r * 68];
        int row = bb * LL + l0 + r;
        #pragma unroll
        for (int j = 0; j < 16; j++) {
            int c = q * 16 + j;
            float a = dt_proj_b[c] + dt.x * dt_proj_w[c * 4] + dt.y * dt_proj_w[c * 4 + 1]
                    + dt.z * dt_proj_w[c * 4 + 2] + dt.w * dt_proj_w[c * 4 + 3];
            float sp = (a > 20.f) ? a : log1pf(expf(a));
            delta_g[(size_t)row * DI + c] = sp;
        }
    }
}

// ================= scan: grid 256 = (b, channel-eighth), 512 thr ======
__global__ __launch_bounds__(512, 1) void k_scan(
    const float* __restrict__ delta_g, const float* __restrict__ xcs_g,
    const float* __restrict__ dbl_g, const float* __restrict__ zs_g,
    const float* __restrict__ A_log, const float* __restrict__ Dp,
    float* __restrict__ y_g) {
    const int t = threadIdx.x;
    const int b = blockIdx.x >> 3, ce = blockIdx.x & 7;
    const int grp = t >> 5, s = t & 31;
    const int c = ce * 16 + grp;
    const size_t r0 = (size_t)(b * LL);
    float Acs = -expf(A_log[c * 32 + s]);
    float Dc = Dp[c];
    float h = 0.f;
    float Bt = dbl_g[r0 * 64 + s], Ct = dbl_g[r0 * 64 + 32 + s];
    float dlt = delta_g[r0 * DI + c], xct = xcs_g[r0 * DI + c];
    float zt = zs_g[r0 * DI + c];
    for (int tt = 0; tt < LL; tt++) {
        float Bn = 0.f, Cn = 0.f, zn = 0.f, dn = 0.f, xn = 0.f;
        if (tt < LL - 1) {
            size_t rn = r0 + tt + 1;
            Bn = dbl_g[rn * 64 + s]; Cn = dbl_g[rn * 64 + 32 + s];
            dn = delta_g[rn * DI + c]; xn = xcs_g[rn * DI + c];
            zn = zs_g[rn * DI + c];
        }
        h = expf(dlt * Acs) * h + (dlt * Bt) * xct;
        float p = h * Ct;
        #pragma unroll
        for (int off = 16; off; off >>= 1) p += __shfl_xor(p, off, 32);
        if (s == 0) y_g[(r0 + tt) * DI + c] = (p + Dc * xct) * zt;
        dlt = dn; xct = xn; Bt = Bn; Ct = Cn; zt = zn;
    }
}

// ================= out_proj + scale 2^18 -> fp16 ==========
__global__ void k_outproj(const float* __restrict__ y, const float* __restrict__ w,
                          _Float16* __restrict__ outp_h) {
    int row = blockIdx.x;
    int d = threadIdx.x;
    __shared__ float ys[DI];
    ys[d] = y[(size_t)row * DI + d];
    ys[d + 64] = y[(size_t)row * DI + d + 64];
    __syncthreads();
    float acc = 0.f;
    const float* wr = w + d * DI;
    #pragma unroll
    for (int c = 0; c < DI; c++) acc += ys[c] * wr[c];
    outp_h[(size_t)row * 64 + d] = (_Float16)(acc * 262144.0f);
}

// ================= emb -> fp16 (* 2^10) ==========
__global__ void k_cvt_emb(const float* __restrict__ emb, _Float16* __restrict__ embh) {
    int i = blockIdx.x * 256 + threadIdx.x;
    int r = i >> 6, d = i & 63;
    float v = (r < NV) ? emb[(size_t)r * 64 + d] * 1024.0f : 0.f;
    embh[i] = (_Float16)v;
}

// ================= logits: 32x256 tiles, 4 blocks/CU (H_concurrency test) ============
// LDS 39.2KB/block -> 4 blocks/CU = 16 waves/CU; stage/MFMA/store phases of different
// blocks overlap. Store phase: 8 LDS reads batched to regs, then 8 nt stores back-to-back.
__global__ __launch_bounds__(256, 4) void k_logits(
    const _Float16* __restrict__ A, const _Float16* __restrict__ Bm,
    float* __restrict__ logits) {
    __shared__ _Float16 As[TM * 68];      // 4.35 KB
    __shared__ _Float16 Bs[TN * 68];      // 34.8 KB, reused as fp32 C tile (32x261 = 33.4 KB)
    const int m0 = blockIdx.x * TM;       // m fastest
    const int n0 = blockIdx.y * TN;
    const int t = threadIdx.x;

    // stage A: 32 rows x 8 chunks = 256 (one per thread)
    {
        int r = t >> 3, c8 = t & 7;
        *(h16x8*)&As[r * 68 + c8 * 8] = *(const h16x8*)&A[(size_t)(m0 + r) * 64 + c8 * 8];
    }
    // stage B: 256 rows x 8 chunks -> 8 per thread
    #pragma unroll
    for (int q = 0; q < 8; q++) {
        int idx = t + q * 256;
        int r = idx >> 3, c8 = idx & 7;
        *(h16x8*)&Bs[r * 68 + c8 * 8] = *(const h16x8*)&Bm[(size_t)(n0 + r) * 64 + c8 * 8];
    }
    __syncthreads();

    const int lane = t & 63, wv = t >> 6;   // wave -> 64-col window
    const int lr = lane & 15, lg = lane >> 4;
    f32x4 acc[2][4];
    #pragma unroll
    for (int mi = 0; mi < 2; mi++)
        #pragma unroll
        for (int ni = 0; ni < 4; ni++)
            acc[mi][ni] = f32x4{0.f, 0.f, 0.f, 0.f};

    #pragma unroll
    for (int step = 0; step < 2; step++) {
        int kb = step * 32 + lg * 8;
        h16x8 a[2], b[4];
        #pragma unroll
        for (int mi = 0; mi < 2; mi++)
            a[mi] = *(const h16x8*)&As[(16 * mi + lr) * 68 + kb];
        #pragma unroll
        for (int ni = 0; ni < 4; ni++)
            b[ni] = *(const h16x8*)&Bs[(64 * wv + 16 * ni + lr) * 68 + kb];
        #pragma unroll
        for (int mi = 0; mi < 2; mi++)
            #pragma unroll
            for (int ni = 0; ni < 4; ni++)
                acc[mi][ni] = __builtin_amdgcn_mfma_f32_16x16x32_f16(a[mi], b[ni], acc[mi][ni], 0, 0, 0);
    }
    __syncthreads();   // all waves done reading Bs

    // transpose epilogue: acc -> C (fp32, pitch 261)
    float* Cs = (float*)Bs;
    const float SC = 3.7252902984619140625e-09f;   // 2^-28
    #pragma unroll
    for (int mi = 0; mi < 2; mi++)
        #pragma unroll
        for (int ni = 0; ni < 4; ni++) {
            int col = 64 * wv + 16 * ni + lr;
            #pragma unroll
            for (int j = 0; j < 4; j++) {
                int row = 16 * mi + 4 * lg + j;
                Cs[row * CPX + col] = acc[mi][ni][j] * SC;
            }
        }
    __syncthreads();

    // store phase: 8 threads/row; batch 8 LDS reads to regs, then 8 nt stores.
    {
        const int r = t >> 3, sc = t & 7;
        const int grow = m0 + r;
        const int shift = (4 - (grow & 3)) & 3;    // (r+shift)%4==0; CPX%4==1 keeps LDS aligned
        float* __restrict__ dst = logits + (size_t)grow * NV + n0;
        const float* src = Cs + r * CPX;
        f32x4 vals[8];
        #pragma unroll
        for (int it = 0; it < 8; it++) {
            int col = shift + 4 * (it * 8 + sc);
            vals[it] = *(const f32x4*)&src[col];   // col <= shift+252 <= 255; reads <= 258 < 261
        }
        if (sc == 0) {
            for (int e = 0; e < shift; e++)
                if (n0 + e < NV) __builtin_nontemporal_store(src[e], &dst[e]);
        }
        #pragma unroll
        for (int it = 0; it < 8; it++) {
            int col = shift + 4 * (it * 8 + sc);
            int gc = n0 + col;
            if (col + 3 < TN && gc + 3 < NV) {
                __builtin_nontemporal_store(vals[it], (f32x4*)&dst[col]);
            } else {
                #pragma unroll
                for (int e = 0; e < 4; e++)
                    if (col + e < TN && gc + e < NV)
                        __builtin_nontemporal_store(vals[it][e], &dst[col + e]);
            }
        }
    }
}

extern "C" void kernel_launch(void* const* d_in, const int* in_sizes, int n_in,
                              void* d_out, int out_size, void* d_ws, size_t ws_size,
                              hipStream_t stream) {
    const int*   ids       = (const int*)  d_in[0];
    const float* item_emb  = (const float*)d_in[1];
    const float* pos_emb   = (const float*)d_in[2];
    const float* in_proj_w = (const float*)d_in[3];
    const float* conv_w    = (const float*)d_in[4];
    const float* conv_b    = (const float*)d_in[5];
    const float* x_proj_w  = (const float*)d_in[6];
    const float* dt_proj_w = (const float*)d_in[7];
    const float* dt_proj_b = (const float*)d_in[8];
    const float* A_log     = (const float*)d_in[9];
    const float* Dp        = (const float*)d_in[10];
    const float* out_proj_w= (const float*)d_in[11];
    float* logits = (float*)d_out;

    float* ws     = (float*)d_ws;
    float* zs     = ws;                      // BL*128  (silu(z))
    float* xcs    = zs + (size_t)BL * DI;    // BL*128
    float* dblg   = xcs + (size_t)BL * DI;   // BL*64   (B|C)
    float* deltag = dblg + (size_t)BL * 64;  // BL*128
    float* yg     = deltag + (size_t)BL * DI;                 // BL*128
    _Float16* outph = (_Float16*)(yg + (size_t)BL * DI);      // BL*64 halves
    _Float16* embh  = outph + (size_t)BL * 64;                // NPAD3*64 halves

    k_cvt_emb<<<(NPAD3 * 64) / 256, 256, 0, stream>>>(item_emb, embh);
    k_pre<<<64, 512, 0, stream>>>(ids, item_emb, pos_emb, in_proj_w, conv_w, conv_b,
                                  x_proj_w, dt_proj_w, dt_proj_b,
                                  zs, xcs, dblg, deltag);
    k_scan<<<256, 512, 0, stream>>>(deltag, xcs, dblg, zs, A_log, Dp, yg);
    k_outproj<<<BL, 64, 0, stream>>>(yg, out_proj_w, outph);
    dim3 lgd(BL / TM, NT3);   // x = 128 m-tiles (fastest), y = 196 n-tiles
    k_logits<<<lgd, 256, 0, stream>>>(outph, embh, logits);
}

// Round 13
// 367.736 us; speedup vs baseline: 1.8384x; 1.8384x over previous
//
#include <hip/hip_runtime.h>
#include <math.h>

#define BB 32
#define LL 128
#define DM 64
#define DI 128
#define NV 50001
#define BL (BB*LL)       // 4096
#define TM 32
#define TN 512
#define NT2 98           // ceil(50001/512)
#define NPAD2 (NT2*TN)   // 50176

typedef float f32x4 __attribute__((ext_vector_type(4)));
typedef _Float16 h16x8 __attribute__((ext_vector_type(8)));

__device__ __forceinline__ float silu_f(float x) { return x / (1.0f + expf(-x)); }

// ================= fused pre-chain v2: 256 blocks = (b, token-eighth), 512 thr ==============
// 16 tokens (+3 halo) per block; weights register-resident; LDS rows broadcast-read.
__global__ __launch_bounds__(512, 1) void k_pre(
    const int* __restrict__ ids, const float* __restrict__ item_emb,
    const float* __restrict__ pos_emb, const float* __restrict__ in_proj_w,
    const float* __restrict__ conv_w, const float* __restrict__ conv_b,
    const float* __restrict__ x_proj_w, const float* __restrict__ dt_proj_w,
    const float* __restrict__ dt_proj_b,
    float* __restrict__ zs_g, float* __restrict__ xcs_g,
    float* __restrict__ dbl_g, float* __restrict__ delta_g) {
    __shared__ float sq[19 * 68];     // embed rows (token T0-3+i), pitch 68
    __shared__ float px[19 * 132];    // x-half of in_proj, pitch 132
    __shared__ float cvS[16 * 132];   // conv+silu rows (token T0+j)
    __shared__ float dtS[16 * 4];     // dt ranks per token
    const int t = threadIdx.x;
    const int bb = blockIdx.x >> 3, e8 = blockIdx.x & 7;
    const int T0 = e8 * 16;

    // ---- phase 1: embedding ----
    {
        int d = t & 63;
        for (int i = t >> 6; i < 19; i += 8) {
            int tl = T0 - 3 + i;
            float v = 0.f;
            if (tl >= 0) {
                int id = ids[bb * LL + tl];
                if (id != 0) v = item_emb[id * DM + d] * 8.0f + pos_emb[tl * DM + d];
            }
            sq[i * 68 + d] = v;
        }
    }
    __syncthreads();
    // ---- phase 2: in_proj; thread owns col e, w-row in 16 f32x4 regs ----
    {
        int e = t & 255, half = t >> 8;
        f32x4 w4[16];
        const float* wr = in_proj_w + e * DM;
        #pragma unroll
        for (int k = 0; k < 16; k++) w4[k] = *(const f32x4*)&wr[4 * k];
        int i0 = half ? 10 : 0, i1 = half ? 19 : 10;
        for (int i = i0; i < i1; i++) {
            float a = 0.f;
            #pragma unroll
            for (int k = 0; k < 16; k++) {
                f32x4 s = *(const f32x4*)&sq[i * 68 + 4 * k];   // wave-uniform row: broadcast
                a += s.x * w4[k].x + s.y * w4[k].y + s.z * w4[k].z + s.w * w4[k].w;
            }
            if (e < 128) px[i * 132 + e] = a;
            else if (i >= 3) zs_g[(size_t)(bb * LL + T0 + i - 3) * DI + (e - 128)] = silu_f(a);
        }
    }
    __syncthreads();
    // ---- phase 3: causal conv + silu ----
    {
        int c = t & 127;
        float cw0 = conv_w[c * 4], cw1 = conv_w[c * 4 + 1];
        float cw2 = conv_w[c * 4 + 2], cw3 = conv_w[c * 4 + 3];
        float cb = conv_b[c];
        #pragma unroll
        for (int m = 0; m < 4; m++) {
            int j = 4 * m + (t >> 7);      // wave-uniform j; token T0+j uses px rows j..j+3
            float v = silu_f(cb + px[j * 132 + c] * cw0 + px[(j + 1) * 132 + c] * cw1
                                + px[(j + 2) * 132 + c] * cw2 + px[(j + 3) * 132 + c] * cw3);
            cvS[j * 132 + c] = v;
            xcs_g[(size_t)(bb * LL + T0 + j) * DI + c] = v;
        }
    }
    __syncthreads();
    // ---- phase 4: x_proj; main covers e=4..67 (B|C), w-row in 32 f32x4 regs ----
    {
        int e = 4 + (t & 63), jg = t >> 6;   // jg 0..7 -> rows jg, jg+8
        f32x4 w4[32];
        const float* wr = x_proj_w + (size_t)e * DI;
        #pragma unroll
        for (int k = 0; k < 32; k++) w4[k] = *(const f32x4*)&wr[4 * k];
        #pragma unroll
        for (int jj = 0; jj < 2; jj++) {
            int j = jg + 8 * jj;
            float a = 0.f;
            #pragma unroll
            for (int k = 0; k < 32; k++) {
                f32x4 x = *(const f32x4*)&cvS[j * 132 + 4 * k];
                a += x.x * w4[k].x + x.y * w4[k].y + x.z * w4[k].z + x.w * w4[k].w;
            }
            dbl_g[(size_t)(bb * LL + T0 + j) * 64 + (e - 4)] = a;
        }
        // dt ranks e=0..3: 64 threads, one dot each
        if (t < 64) {
            int j2 = t >> 2, e2 = t & 3;
            const float* wr2 = x_proj_w + (size_t)e2 * DI;
            float a = 0.f;
            #pragma unroll
            for (int k = 0; k < 32; k++) {
                f32x4 x = *(const f32x4*)&cvS[j2 * 132 + 4 * k];
                f32x4 w2 = *(const f32x4*)&wr2[4 * k];
                a += x.x * w2.x + x.y * w2.y + x.z * w2.z + x.w * w2.w;
            }
            dtS[j2 * 4 + e2] = a;
        }
    }
    __syncthreads();
    // ---- phase 5: delta = softplus(dt @ dt_proj^T + b) ----
    {
        int c = t & 127;
        float dw0 = dt_proj_w[c * 4], dw1 = dt_proj_w[c * 4 + 1];
        float dw2 = dt_proj_w[c * 4 + 2], dw3 = dt_proj_w[c * 4 + 3];
        float db = dt_proj_b[c];
        #pragma unroll
        for (int m = 0; m < 4; m++) {
            int j = 4 * m + (t >> 7);
            float a = db + dtS[j * 4] * dw0 + dtS[j * 4 + 1] * dw1
                         + dtS[j * 4 + 2] * dw2 + dtS[j * 4 + 3] * dw3;
            float sp = (a > 20.f) ? a : log1pf(expf(a));
            delta_g[(size_t)(bb * LL + T0 + j) * DI + c] = sp;
        }
    }
}

// ================= scan: grid 256 = (b, channel-eighth), 512 thr ======
__global__ __launch_bounds__(512, 1) void k_scan(
    const float* __restrict__ delta_g, const float* __restrict__ xcs_g,
    const float* __restrict__ dbl_g, const float* __restrict__ zs_g,
    const float* __restrict__ A_log, const float* __restrict__ Dp,
    float* __restrict__ y_g) {
    const int t = threadIdx.x;
    const int b = blockIdx.x >> 3, ce = blockIdx.x & 7;
    const int grp = t >> 5, s = t & 31;
    const int c = ce * 16 + grp;
    const size_t r0 = (size_t)(b * LL);
    float Acs = -expf(A_log[c * 32 + s]);
    float Dc = Dp[c];
    float h = 0.f;
    float Bt = dbl_g[r0 * 64 + s], Ct = dbl_g[r0 * 64 + 32 + s];
    float dlt = delta_g[r0 * DI + c], xct = xcs_g[r0 * DI + c];
    float zt = zs_g[r0 * DI + c];
    for (int tt = 0; tt < LL; tt++) {
        float Bn = 0.f, Cn = 0.f, zn = 0.f, dn = 0.f, xn = 0.f;
        if (tt < LL - 1) {
            size_t rn = r0 + tt + 1;
            Bn = dbl_g[rn * 64 + s]; Cn = dbl_g[rn * 64 + 32 + s];
            dn = delta_g[rn * DI + c]; xn = xcs_g[rn * DI + c];
            zn = zs_g[rn * DI + c];
        }
        h = expf(dlt * Acs) * h + (dlt * Bt) * xct;
        float p = h * Ct;
        #pragma unroll
        for (int off = 16; off; off >>= 1) p += __shfl_xor(p, off, 32);
        if (s == 0) y_g[(r0 + tt) * DI + c] = (p + Dc * xct) * zt;
        dlt = dn; xct = xn; Bt = Bn; Ct = Cn; zt = zn;
    }
}

// ================= out_proj v2: 512 blocks x 256 thr, 8 rows/block, w in regs ==========
__global__ __launch_bounds__(256, 2) void k_outproj(
    const float* __restrict__ y, const float* __restrict__ w,
    _Float16* __restrict__ outp_h) {
    __shared__ float ys[8 * 132];
    const int t = threadIdx.x;
    const int r0 = blockIdx.x * 8;
    {
        int r = t >> 5, c4 = t & 31;
        *(f32x4*)&ys[r * 132 + 4 * c4] = *(const f32x4*)&y[(size_t)(r0 + r) * DI + 4 * c4];
    }
    __syncthreads();
    int d = t & 63, rh = t >> 6;
    f32x4 w4[32];
    const float* wr = w + d * DI;
    #pragma unroll
    for (int k = 0; k < 32; k++) w4[k] = *(const f32x4*)&wr[4 * k];
    #pragma unroll
    for (int jj = 0; jj < 2; jj++) {
        int r = rh + 4 * jj;
        float a = 0.f;
        #pragma unroll
        for (int k = 0; k < 32; k++) {
            f32x4 x = *(const f32x4*)&ys[r * 132 + 4 * k];
            a += x.x * w4[k].x + x.y * w4[k].y + x.z * w4[k].z + x.w * w4[k].w;
        }
        outp_h[(size_t)(r0 + r) * 64 + d] = (_Float16)(a * 262144.0f);   // * 2^18
    }
}

// ================= emb -> fp16 (* 2^10) ==========
__global__ void k_cvt_emb(const float* __restrict__ emb, _Float16* __restrict__ embh) {
    int i = blockIdx.x * 256 + threadIdx.x;
    int r = i >> 6, d = i & 63;
    float v = (r < NV) ? emb[(size_t)r * 64 + d] * 1024.0f : 0.f;
    embh[i] = (_Float16)v;
}

// ================= logits (R11 exact — measured best): 32x512 tiles, nt stores ==========
__global__ __launch_bounds__(256, 2) void k_logits(
    const _Float16* __restrict__ A, const _Float16* __restrict__ Bm,
    float* __restrict__ logits) {
    __shared__ _Float16 As[TM * 72];      // 4.6 KB
    __shared__ _Float16 Bs[TN * 72];      // 73.7 KB, reused as fp32 C tile
    const int m0 = blockIdx.x * TM;       // m fastest
    const int n0 = blockIdx.y * TN;
    const int t = threadIdx.x;

    {
        int r = t >> 3, c8 = t & 7;
        *(h16x8*)&As[r * 72 + c8 * 8] = *(const h16x8*)&A[(size_t)(m0 + r) * 64 + c8 * 8];
    }
    #pragma unroll
    for (int q = 0; q < 16; q++) {
        int idx = t + q * 256;
        int r = idx >> 3, c8 = idx & 7;
        *(h16x8*)&Bs[r * 72 + c8 * 8] = *(const h16x8*)&Bm[(size_t)(n0 + r) * 64 + c8 * 8];
    }
    __syncthreads();

    const int lane = t & 63, wv = t >> 6;
    const int lr = lane & 15, lg = lane >> 4;
    f32x4 acc[2][8];
    #pragma unroll
    for (int mi = 0; mi < 2; mi++)
        #pragma unroll
        for (int ni = 0; ni < 8; ni++)
            acc[mi][ni] = f32x4{0.f, 0.f, 0.f, 0.f};

    #pragma unroll
    for (int step = 0; step < 2; step++) {
        int kb = step * 32 + lg * 8;
        h16x8 a[2], b[8];
        #pragma unroll
        for (int mi = 0; mi < 2; mi++)
            a[mi] = *(const h16x8*)&As[(16 * mi + lr) * 72 + kb];
        #pragma unroll
        for (int ni = 0; ni < 8; ni++)
            b[ni] = *(const h16x8*)&Bs[(128 * wv + 16 * ni + lr) * 72 + kb];
        #pragma unroll
        for (int mi = 0; mi < 2; mi++)
            #pragma unroll
            for (int ni = 0; ni < 8; ni++)
                acc[mi][ni] = __builtin_amdgcn_mfma_f32_16x16x32_f16(a[mi], b[ni], acc[mi][ni], 0, 0, 0);
    }
    __syncthreads();

    float* Cs = (float*)Bs;
    const float SC = 3.7252902984619140625e-09f;   // 2^-28
    #pragma unroll
    for (int mi = 0; mi < 2; mi++)
        #pragma unroll
        for (int ni = 0; ni < 8; ni++) {
            int col = 128 * wv + 16 * ni + lr;
            #pragma unroll
            for (int j = 0; j < 4; j++) {
                int row = 16 * mi + 4 * lg + j;
                Cs[row * 517 + col] = acc[mi][ni][j] * SC;
            }
        }
    __syncthreads();

    #pragma unroll
    for (int q = 0; q < 16; q++) {
        int r = 2 * q + (t >> 7);
        int c = t & 127;
        int grow = m0 + r;
        int s = (4 - (grow & 3)) & 3;
        float* dst = logits + (size_t)grow * NV + n0;
        const float* src = Cs + r * 517;
        if (s == 0) {
            int col = 4 * c;
            int gc = n0 + col;
            if (gc + 3 < NV) {
                __builtin_nontemporal_store(*(const f32x4*)&src[col], (f32x4*)&dst[col]);
            } else {
                #pragma unroll
                for (int e = 0; e < 4; e++)
                    if (gc + e < NV) __builtin_nontemporal_store(src[col + e], &dst[col + e]);
            }
        } else {
            if (c == 0) {
                for (int e = 0; e < s; e++)
                    if (n0 + e < NV) __builtin_nontemporal_store(src[e], &dst[e]);
            }
            if (c < 127) {
                int col = s + 4 * c;
                int gc = n0 + col;
                if (gc + 3 < NV) {
                    __builtin_nontemporal_store(*(const f32x4*)&src[col], (f32x4*)&dst[col]);
                } else {
                    #pragma unroll
                    for (int e = 0; e < 4; e++)
                        if (gc + e < NV) __builtin_nontemporal_store(src[col + e], &dst[col + e]);
                }
            } else {
                for (int e = s + 508; e < 512; e++)
                    if (n0 + e < NV) __builtin_nontemporal_store(src[e], &dst[e]);
            }
        }
    }
}

extern "C" void kernel_launch(void* const* d_in, const int* in_sizes, int n_in,
                              void* d_out, int out_size, void* d_ws, size_t ws_size,
                              hipStream_t stream) {
    const int*   ids       = (const int*)  d_in[0];
    const float* item_emb  = (const float*)d_in[1];
    const float* pos_emb   = (const float*)d_in[2];
    const float* in_proj_w = (const float*)d_in[3];
    const float* conv_w    = (const float*)d_in[4];
    const float* conv_b    = (const float*)d_in[5];
    const float* x_proj_w  = (const float*)d_in[6];
    const float* dt_proj_w = (const float*)d_in[7];
    const float* dt_proj_b = (const float*)d_in[8];
    const float* A_log     = (const float*)d_in[9];
    const float* Dp        = (const float*)d_in[10];
    const float* out_proj_w= (const float*)d_in[11];
    float* logits = (float*)d_out;

    float* ws     = (float*)d_ws;
    float* zs     = ws;                      // BL*128  (silu(z))
    float* xcs    = zs + (size_t)BL * DI;    // BL*128
    float* dblg   = xcs + (size_t)BL * DI;   // BL*64   (B|C)
    float* deltag = dblg + (size_t)BL * 64;  // BL*128
    float* yg     = deltag + (size_t)BL * DI;                 // BL*128
    _Float16* outph = (_Float16*)(yg + (size_t)BL * DI);      // BL*64 halves
    _Float16* embh  = outph + (size_t)BL * 64;                // NPAD2*64 halves

    k_cvt_emb<<<(NPAD2 * 64) / 256, 256, 0, stream>>>(item_emb, embh);
    k_pre<<<256, 512, 0, stream>>>(ids, item_emb, pos_emb, in_proj_w, conv_w, conv_b,
                                   x_proj_w, dt_proj_w, dt_proj_b,
                                   zs, xcs, dblg, deltag);
    k_scan<<<256, 512, 0, stream>>>(deltag, xcs, dblg, zs, A_log, Dp, yg);
    k_outproj<<<BL / 8, 256, 0, stream>>>(yg, out_proj_w, outph);
    dim3 lgd(BL / TM, NT2);   // x = 128 m-tiles (fastest), y = 98 n-tiles
    k_logits<<<lgd, 256, 0, stream>>>(outph, embh, logits);
}